// Round 6
// baseline (421.833 us; speedup 1.0000x reference)
//
#include <hip/hip_runtime.h>

// MixedLayerCond round 6: round-5 design with the staging source bug fixed
// (h*1024 -> h*512: a global xt row is 32 cols x 32 ci = 1024 ushorts, so a
// 16-col half-row run spans 512 ushorts).
//
//  prep (ONE dispatch): pw blocks [0,4096) + px blocks [4096,12288) + sched.
//    px: one thread = one 16B granule of xt[b][cc][hw][ci32] (coalesced store).
//    pw: w OIHW fp32 -> wt[a][cc][oc][khw][ci32] via LDS transpose.
//    sched: LPT tile list. heavy (k>=5) sample = 32 tiles (64oc x 4rows),
//    light = 16 tiles (128oc x 4rows). T = 1024 + 16*nh.
//  conv: grid 1024, 4 blocks/CU (launch_bounds(256,4)), work-steal tiles.
//    x staged per cc via global_load_lds width=16 (LDS unpadded, 16-col run
//    = contiguous 1KB -> conflict-free b128 reads), zero-filled OOB rows,
//    halo cols zeroed once. af weights double-buffered from global (L2-hot).

typedef unsigned short ushort_t;
typedef __attribute__((ext_vector_type(8))) short short8;
typedef __attribute__((ext_vector_type(4))) float f32x4;

#define CIN   256
#define COUT  256
#define HH    32
#define WW    32
#define HW    1024

// ws layout (ushort elements)
#define XT_ELEMS   16777216            // 64*8*1024*32
#define WT_OFF_0   0
#define WT_OFF_1   65536               // 8*256*1*32
#define WT_OFF_2   655360              // + 8*256*9*32
#define WT_OFF_3   2293760             // + 8*256*25*32
#define WT_ELEMS   5505024             // + 8*256*49*32
#define TILE_BYTE_OFF ((size_t)(XT_ELEMS + WT_ELEMS) * 2)
#define MAX_TILES  2048
#define WS_NEEDED  (TILE_BYTE_OFF + MAX_TILES * 2 + 64)

// LDS x tile: up to 10 rows x 38 cols x 32 ushorts (unpadded; interior cols
// 3..34 are contiguous per row => global_load_lds lane*16B constraint holds)
#define XS_R_STRIDE 1216               // 38*32
#define XS_ELEMS    12160              // 10 rows (24.3 KB)

__device__ inline ushort_t f2bf(float f) {
    unsigned x = __builtin_bit_cast(unsigned, f);
    unsigned r = (x + 0x7FFFu + ((x >> 16) & 1u)) >> 16;
    return (ushort_t)r;
}

__device__ inline void gld16(const ushort_t* g, ushort_t* l) {
    __builtin_amdgcn_global_load_lds(
        (const __attribute__((address_space(1))) unsigned int*)g,
        (__attribute__((address_space(3))) unsigned int*)l, 16, 0, 0);
}

// ---------------- fused pre-pass: pw + px + sched ----------------
__global__ __launch_bounds__(256) void prep_kernel(
    const float* __restrict__ x,
    const float* __restrict__ w0, const float* __restrict__ w1,
    const float* __restrict__ w2, const float* __restrict__ w3,
    const int* __restrict__ arc,
    ushort_t* __restrict__ xt, ushort_t* __restrict__ wt,
    ushort_t* __restrict__ tiles, unsigned* __restrict__ cnt) {
    __shared__ float lds[2 * 32 * 49];
    const int blk = blockIdx.x;
    const int tid = threadIdx.x;

    if (blk < 4096) {                  // ---- pw: weight transform ----
        const int a   = blk >> 10;
        const int cc  = (blk >> 7) & 7;
        const int oc0 = (blk & 127) * 2;
        const int kk  = (a == 0) ? 1 : (a == 1) ? 9 : (a == 2) ? 25 : 49;
        const float* __restrict__ w = (a == 0) ? w0 : (a == 1) ? w1
                                    : (a == 2) ? w2 : w3;
        const size_t woff = (a == 0) ? WT_OFF_0 : (a == 1) ? WT_OFF_1
                          : (a == 2) ? WT_OFF_2 : WT_OFF_3;
        const int ckk = 32 * kk;
#pragma unroll
        for (int ocq = 0; ocq < 2; ++ocq) {
            const float* src = w + ((size_t)((oc0 + ocq) * CIN + cc * 32)) * kk;
            for (int i = tid; i < ckk; i += 256) lds[ocq * ckk + i] = src[i];
        }
        __syncthreads();
        ushort_t* dst = wt + woff + ((size_t)(cc * COUT + oc0)) * kk * 32;
        const int F = 2 * kk * 32;
        for (int j = tid; j < F; j += 256) {
            const int ci  = j & 31;
            const int t2  = j >> 5;
            const int khw = t2 % kk;
            const int ocq = t2 / kk;
            dst[j] = f2bf(lds[ocq * ckk + ci * kk + khw]);
        }
    } else if (blk < 12288) {          // ---- px: one thread = one granule ----
        const int g  = (blk - 4096) * 256 + tid;      // 2,097,152 granules
        const int q8 = g & 3;
        const int hw = (g >> 2) & 1023;
        const int cc = (g >> 12) & 7;
        const int b  = g >> 15;
        const float* src = x + ((size_t)(b * CIN + cc * 32 + q8 * 8)) * HW + hw;
        short8 o;
#pragma unroll
        for (int j = 0; j < 8; ++j)
            o[j] = (short)f2bf(src[(size_t)j * HW]);
        *(short8*)(xt + (size_t)g * 8) = o;           // fully coalesced
    } else if (tid < 64) {             // ---- sched: LPT tile list ----
        const int lane = tid;          // == sample b
        const int ab = (int)arc[lane];
        unsigned long long m[4];
#pragma unroll
        for (int v = 0; v < 4; ++v) m[v] = __ballot(ab == v);
        int gt = 0;
#pragma unroll
        for (int v = 1; v < 4; ++v) if (v > ab) gt += __popcll(m[v]);
        const unsigned long long eq = (ab == 0) ? m[0] : (ab == 1) ? m[1]
                                    : (ab == 2) ? m[2] : m[3];
        const unsigned long long lower = (lane == 0) ? 0ull
                                       : (~0ull >> (64 - lane));
        const int rank = gt + __popcll(eq & lower);
        const int nh   = __popcll(m[2]) + __popcll(m[3]);
        const bool heavy = (ab >= 2);
        const int myCnt = heavy ? 32 : 16;
        const int start = heavy ? 32 * rank : 32 * nh + 16 * (rank - nh);
        for (int j = 0; j < myCnt; ++j)
            tiles[start + j] = (ushort_t)((lane << 5) | j);
        if (lane == 0) { cnt[0] = 0u; cnt[1] = (unsigned)(1024 + 16 * nh); }
    }
}

// ---------------- main: MFMA conv body ----------------
// Tile = (MT*32) oc x 4 rows. Wave tile = (MT*16) oc x 64 pos.
template <int K, int MT>
__device__ void conv_body(const ushort_t* __restrict__ xt,
                          const ushort_t* __restrict__ wtb,
                          const float* __restrict__ eb,
                          int b, int cls, int oc0, int r0,
                          float* __restrict__ out, ushort_t* xs) {
    constexpr int KK  = K * K;
    constexpr int PAD = K / 2;
    constexpr int R   = 4 + 2 * PAD;   // staged rows (max 10)

    const int tid  = threadIdx.x;
    const int wave = tid >> 6;
    const int lane = tid & 63;
    const int wm   = wave >> 1;        // oc half
    const int wn   = wave & 1;         // pos half (64 of 128)
    const int ln   = lane & 15;
    const int q    = lane >> 4;

    f32x4 acc[MT][4];
#pragma unroll
    for (int mt = 0; mt < MT; ++mt)
#pragma unroll
        for (int nt = 0; nt < 4; ++nt) acc[mt][nt] = (f32x4)0.0f;

    const int ocw = oc0 + wm * (MT * 16);
    const ushort_t* wcol = wtb + ((size_t)(ocw + ln) * KK) * 32 + q * 8;
    short8 afp[MT];
#pragma unroll
    for (int mt = 0; mt < MT; ++mt)
        afp[mt] = *(const short8*)&wcol[(size_t)(mt * 16 * KK) * 32];

    const ushort_t* xsrc = xt + ((size_t)b * 8) * (HW * 32);

    for (int cc = 0; cc < 8; ++cc) {
        __syncthreads();
        // stage R rows x 32 cols x 32 ci via global->LDS DMA (16B/lane).
        // One run = one half-row: 16 cols x 32 ci = 512 ushorts = 64 lanes*16B.
#pragma unroll
        for (int i = 0; i < R / 2; ++i) {
            const int run = i * 4 + wave;            // wave-uniform
            const int r   = run >> 1;
            const int h   = run & 1;
            const int gr  = r0 - PAD + r;
            ushort_t* ldst = xs + r * XS_R_STRIDE + 96 + h * 512;
            if (gr >= 0 && gr < HH) {
                const ushort_t* src =
                    xsrc + ((size_t)(cc * HW + gr * WW)) * 32 + h * 512 + lane * 8;
                gld16(src, ldst);
            } else {
                *(short8*)(ldst + lane * 8) = (short8)0;
            }
        }
        __syncthreads();

        const ushort_t* wb = wcol + ((size_t)cc * COUT * KK) * 32;
#pragma unroll 1
        for (int kh = 0; kh < K; ++kh) {
#pragma unroll
            for (int kw = 0; kw < K; ++kw) {
                const int khw = kh * K + kw;
                short8 afc[MT];
#pragma unroll
                for (int mt = 0; mt < MT; ++mt) afc[mt] = afp[mt];
                {   // prefetch next khw (or next cc's khw=0)
                    int nkhw = khw + 1;
                    const ushort_t* nb = wb;
                    if (nkhw == KK) {
                        nkhw = 0;
                        if (cc < 7) nb = wb + ((size_t)COUT * KK) * 32;
                    }
#pragma unroll
                    for (int mt = 0; mt < MT; ++mt)
                        afp[mt] = *(const short8*)&nb[(size_t)(mt * 16 * KK + nkhw) * 32];
                }
                short8 bf[4];
#pragma unroll
                for (int nt = 0; nt < 4; ++nt) {
                    const int rl = wn * 2 + (nt >> 1) + kh;
                    const int c  = (nt & 1) * 16 + ln + 3 + (kw - PAD);
                    bf[nt] = *(const short8*)&xs[rl * XS_R_STRIDE + c * 32 + q * 8];
                }
#pragma unroll
                for (int mt = 0; mt < MT; ++mt)
#pragma unroll
                    for (int nt = 0; nt < 4; ++nt)
                        acc[mt][nt] = __builtin_amdgcn_mfma_f32_16x16x32_bf16(
                            afc[mt], bf[nt], acc[mt][nt], 0, 0, 0);
            }
        }
    }

    // epilogue: C/D layout col=lane&15 (pos), row=q*4+reg (oc)
#pragma unroll
    for (int mt = 0; mt < MT; ++mt) {
#pragma unroll
        for (int i = 0; i < 4; ++i) {
            const int oc = ocw + mt * 16 + q * 4 + i;
            const float ev = eb[(size_t)cls * COUT + oc];
            float* ob = out + ((size_t)(b * COUT + oc)) * HW;
#pragma unroll
            for (int nt = 0; nt < 4; ++nt) {
                const int row = r0 + wn * 2 + (nt >> 1);
                const int col = (nt & 1) * 16 + ln;
                ob[row * WW + col] = acc[mt][nt][i] + ev;
            }
        }
    }
}

__global__ __launch_bounds__(256, 4) void conv_mfma(
    const ushort_t* __restrict__ xt, const ushort_t* __restrict__ wt,
    const int* __restrict__ y, const int* __restrict__ arc,
    const float* __restrict__ e0, const float* __restrict__ e1,
    const float* __restrict__ e2, const float* __restrict__ e3,
    float* __restrict__ out,
    const ushort_t* __restrict__ tiles, unsigned* __restrict__ cnt) {
    __shared__ ushort_t xs[XS_ELEMS];
    __shared__ int t_sh;
    const int tid = threadIdx.x;
    const unsigned T = cnt[1];

    // zero column halo once (cols 0-2, 35-37; staging never writes them)
    for (int i = tid; i < 240; i += 256) {
        const int g    = i & 3;
        const int cell = i >> 2;
        const int cidx = cell % 6;
        const int r    = cell / 6;
        const int col  = (cidx < 3) ? cidx : cidx + 32;
        *(short8*)&xs[r * XS_R_STRIDE + col * 32 + g * 8] = (short8)0;
    }

    for (;;) {
        if (tid == 0) {
            const unsigned t = atomicAdd(cnt, 1u);
            t_sh = (t < T) ? (int)tiles[t] : -1;
        }
        __syncthreads();
        const int e = t_sh;
        __syncthreads();
        if (e < 0) break;

        const int b   = e >> 5;
        const int j   = e & 31;
        const int a   = __builtin_amdgcn_readfirstlane(arc[b]);
        const int cls = __builtin_amdgcn_readfirstlane(y[b]);
        switch (a) {
            case 0:  conv_body<1, 4>(xt, wt + WT_OFF_0, e0, b, cls,
                                     (j & 1) << 7, (j >> 1) << 2, out, xs); break;
            case 1:  conv_body<3, 4>(xt, wt + WT_OFF_1, e1, b, cls,
                                     (j & 1) << 7, (j >> 1) << 2, out, xs); break;
            case 2:  conv_body<5, 2>(xt, wt + WT_OFF_2, e2, b, cls,
                                     (j & 3) << 6, (j >> 2) << 2, out, xs); break;
            default: conv_body<7, 2>(xt, wt + WT_OFF_3, e3, b, cls,
                                     (j & 3) << 6, (j >> 2) << 2, out, xs); break;
        }
    }
}

// ---------------- fallback (round-1 direct conv) ----------------
__global__ __launch_bounds__(256) void cond_conv_direct(
    const float* __restrict__ x, const int* __restrict__ y,
    const int* __restrict__ arc,
    const float* __restrict__ w0, const float* __restrict__ e0,
    const float* __restrict__ w1, const float* __restrict__ e1,
    const float* __restrict__ w2, const float* __restrict__ e2,
    const float* __restrict__ w3, const float* __restrict__ e3,
    float* __restrict__ out) {
    const int b   = blockIdx.x >> 4;
    const int o0  = (blockIdx.x & 15) << 4;
    const int tid = threadIdx.x;
    const int col  = tid & 31;
    const int row0 = tid >> 5;
    int a   = __builtin_amdgcn_readfirstlane(arc[b]);
    int cls = __builtin_amdgcn_readfirstlane(y[b]);
    const int k   = (a == 0) ? 1 : (a == 1) ? 3 : (a == 2) ? 5 : 7;
    const int kk  = k * k;
    const int pad = k >> 1;
    const float* __restrict__ wp = (a == 0) ? w0 : (a == 1) ? w1 : (a == 2) ? w2 : w3;
    const float* __restrict__ ep = (a == 0) ? e0 : (a == 1) ? e1 : (a == 2) ? e2 : e3;
    __shared__ float xsh[8 * HW];
    float acc[16][4];
#pragma unroll
    for (int o = 0; o < 16; ++o)
#pragma unroll
        for (int p = 0; p < 4; ++p) acc[o][p] = 0.f;
    const float* xb = x + (size_t)b * CIN * HW;
    for (int c0 = 0; c0 < CIN; c0 += 8) {
        __syncthreads();
        const float4* src = (const float4*)(xb + c0 * HW);
        float4* dst = (float4*)xsh;
#pragma unroll
        for (int i = 0; i < 8; ++i) dst[tid + (i << 8)] = src[tid + (i << 8)];
        __syncthreads();
        for (int kh = 0; kh < k; ++kh) {
            const int dh = kh - pad;
            int raddr[4]; bool rok[4];
#pragma unroll
            for (int p = 0; p < 4; ++p) {
                const int rr = row0 + 8 * p + dh;
                rok[p] = (rr >= 0) && (rr < HH);
                raddr[p] = (rok[p] ? rr : 0) * WW;
            }
            for (int kw = 0; kw < k; ++kw) {
                const int cc2 = col + kw - pad;
                const bool cok = (cc2 >= 0) && (cc2 < WW);
                const int cofs = cok ? cc2 : 0;
                const int khw = kh * k + kw;
#pragma unroll
                for (int ci = 0; ci < 8; ++ci) {
                    float xv[4];
#pragma unroll
                    for (int p = 0; p < 4; ++p) {
                        const float v = xsh[ci * HW + raddr[p] + cofs];
                        xv[p] = (rok[p] && cok) ? v : 0.f;
                    }
                    const float* wb = wp + (size_t)o0 * CIN * kk + (size_t)(c0 + ci) * kk + khw;
#pragma unroll
                    for (int o = 0; o < 16; ++o) {
                        const float wsv = wb[(size_t)o * CIN * kk];
#pragma unroll
                        for (int p = 0; p < 4; ++p) acc[o][p] += wsv * xv[p];
                    }
                }
            }
        }
    }
    const float* erow = ep + (size_t)cls * COUT + o0;
    float* ob = out + (size_t)(b * COUT + o0) * HW;
#pragma unroll
    for (int o = 0; o < 16; ++o) {
        const float ev = erow[o];
#pragma unroll
        for (int p = 0; p < 4; ++p)
            ob[o * HW + (row0 + 8 * p) * WW + col] = acc[o][p] + ev;
    }
}

extern "C" void kernel_launch(void* const* d_in, const int* in_sizes, int n_in,
                              void* d_out, int out_size, void* d_ws, size_t ws_size,
                              hipStream_t stream) {
    const float* x   = (const float*)d_in[0];
    const int*   y   = (const int*)  d_in[1];
    const int*   arc = (const int*)  d_in[2];
    const float* w0  = (const float*)d_in[3];
    const float* e0  = (const float*)d_in[4];
    const float* w1  = (const float*)d_in[5];
    const float* e1  = (const float*)d_in[6];
    const float* w2  = (const float*)d_in[7];
    const float* e2  = (const float*)d_in[8];
    const float* w3  = (const float*)d_in[9];
    const float* e3  = (const float*)d_in[10];
    float* out = (float*)d_out;
    const int B = in_sizes[1];

    if (ws_size >= WS_NEEDED && B == 64) {
        ushort_t* xt    = (ushort_t*)d_ws;
        ushort_t* wt    = xt + XT_ELEMS;
        ushort_t* tiles = (ushort_t*)((char*)d_ws + TILE_BYTE_OFF);
        unsigned* cnt   = (unsigned*)((char*)d_ws + TILE_BYTE_OFF + MAX_TILES * 2);
        hipLaunchKernelGGL(prep_kernel, dim3(12289), dim3(256), 0, stream,
                           x, w0, w1, w2, w3, arc, xt, wt, tiles, cnt);
        hipLaunchKernelGGL(conv_mfma, dim3(1024), dim3(256), 0, stream,
                           xt, wt, y, arc, e0, e1, e2, e3, out, tiles, cnt);
    } else {
        hipLaunchKernelGGL(cond_conv_direct, dim3(B * 16), dim3(256), 0, stream,
                           x, y, arc, w0, e0, w1, e1, w2, e2, w3, e3, out);
    }
}